// Round 1
// baseline (432.488 us; speedup 1.0000x reference)
//
#include <hip/hip_runtime.h>

// QuantumLayer: B=8, L=2048, D=512, NQ=10 qubits, 4 layers, DIM=1024.
// One wave (64 lanes) per token; statevector in registers:
//   amplitude index i (10 bits): lane = i>>4 (bits 9..4), reg = i&15 (bits 3..0)
//   qubit q lives at bit b = 9-q of i.
#define NQ 10
#define DQ 512
#define QL 4
#define NTOK (8 * 2048)

__global__ __launch_bounds__(256) void quantum_kernel(
    const float* __restrict__ x, const float* __restrict__ in_W,
    const float* __restrict__ in_b, const float* __restrict__ gamma,
    const float* __restrict__ beta, const float* __restrict__ weights,
    const float* __restrict__ out_W, const float* __restrict__ out_b,
    float* __restrict__ out)
{
    __shared__ float lds_oW[NQ * DQ];   // out_W transposed: [q][d]
    const int t = threadIdx.x;
    for (int idx = t; idx < NQ * DQ; idx += 256) {
        int d = idx / NQ;
        int q = idx - d * NQ;
        lds_oW[q * DQ + d] = out_W[idx];
    }
    __syncthreads();

    const int lane = t & 63;
    const int wv = t >> 6;
    const int tok = blockIdx.x * 4 + wv;

    // ---------------- stage 1: h = tanh(x @ in_W^T + in_b), then LN ----------
    const float* xrow = x + (size_t)tok * DQ;
    float xv[8];
    float h[NQ];
#pragma unroll
    for (int q = 0; q < NQ; ++q) h[q] = 0.f;
#pragma unroll
    for (int k = 0; k < 8; ++k) {
        xv[k] = xrow[lane + 64 * k];
#pragma unroll
        for (int q = 0; q < NQ; ++q)
            h[q] = fmaf(xv[k], in_W[q * DQ + lane + 64 * k], h[q]);
    }
#pragma unroll
    for (int off = 32; off >= 1; off >>= 1) {
#pragma unroll
        for (int q = 0; q < NQ; ++q) h[q] += __shfl_xor(h[q], off);
    }

    float mu = 0.f;
#pragma unroll
    for (int q = 0; q < NQ; ++q) { h[q] = tanhf(h[q] + in_b[q]); mu += h[q]; }
    mu *= 0.1f;
    float var = 0.f;
#pragma unroll
    for (int q = 0; q < NQ; ++q) { float d0 = h[q] - mu; var += d0 * d0; }
    var *= 0.1f;
    const float rstd = rsqrtf(var + 1e-5f);

    // per-token gate angles: c = cos(f/2), s = sin(f/2) (used by RX and phase)
    float cq[NQ], sq[NQ];
#pragma unroll
    for (int q = 0; q < NQ; ++q) {
        float f = (h[q] - mu) * rstd * gamma[q] + beta[q];
        float hf = 0.5f * f;
        cq[q] = __cosf(hf);
        sq[q] = __sinf(hf);
    }

    // ---------------- statevector init: |0...0> ------------------------------
    float sr[16], si[16];
#pragma unroll
    for (int r = 0; r < 16; ++r) { sr[r] = 0.f; si[r] = 0.f; }
    if (lane == 0) sr[0] = 1.f;

    // ---------------- circuit -------------------------------------------------
    for (int l = 0; l < QL; ++l) {
        // ---- RX(feats[q]) on each qubit: U = [[c, -i s],[-i s, c]] ----
#pragma unroll
        for (int q = 0; q < NQ; ++q) {
            const int b = 9 - q;
            const float c = cq[q], s = sq[q];
            if (b >= 4) {
                const int mask = 1 << (b - 4);
#pragma unroll
                for (int r = 0; r < 16; ++r) {
                    float pr = __shfl_xor(sr[r], mask);
                    float pi = __shfl_xor(si[r], mask);
                    sr[r] = fmaf(c, sr[r], s * pi);
                    si[r] = fmaf(c, si[r], -s * pr);
                }
            } else {
                const int bm = 1 << b;
#pragma unroll
                for (int r = 0; r < 16; ++r) {
                    if (!(r & bm)) {
                        const int r1 = r | bm;
                        float a0r = sr[r], a0i = si[r];
                        float a1r = sr[r1], a1i = si[r1];
                        sr[r]  = fmaf(c, a0r,  s * a1i);
                        si[r]  = fmaf(c, a0i, -s * a1r);
                        sr[r1] = fmaf(c, a1r,  s * a0i);
                        si[r1] = fmaf(c, a1i, -s * a0r);
                    }
                }
            }
        }

        // ---- phase gate diag(conj(p), p), p = exp(i f/2): same c,s ----
#pragma unroll
        for (int q = 0; q < NQ; ++q) {
            const int b = 9 - q;
            const float c = cq[q], s = sq[q];
            if (b >= 4) {
                const float ss = (lane & (1 << (b - 4))) ? s : -s;
#pragma unroll
                for (int r = 0; r < 16; ++r) {
                    float ar = sr[r], ai = si[r];
                    sr[r] = fmaf(c, ar, -ss * ai);
                    si[r] = fmaf(c, ai,  ss * ar);
                }
            } else {
#pragma unroll
                for (int r = 0; r < 16; ++r) {
                    const float ss = (r & (1 << b)) ? s : -s;
                    float ar = sr[r], ai = si[r];
                    sr[r] = fmaf(c, ar, -ss * ai);
                    si[r] = fmaf(c, ai,  ss * ar);
                }
            }
        }

        // ---- per-qubit RY(w0) then RZ(w1) (token-independent) ----
        const float* wl = weights + l * NQ * 2;
#pragma unroll
        for (int q = 0; q < NQ; ++q) {
            const int b = 9 - q;
            const float ty = 0.5f * wl[q * 2 + 0];
            const float cy = __cosf(ty), sy = __sinf(ty);
            if (b >= 4) {
                const int mask = 1 << (b - 4);
                const float ss = (lane & mask) ? sy : -sy;
#pragma unroll
                for (int r = 0; r < 16; ++r) {
                    float pr = __shfl_xor(sr[r], mask);
                    float pi = __shfl_xor(si[r], mask);
                    sr[r] = fmaf(cy, sr[r], ss * pr);
                    si[r] = fmaf(cy, si[r], ss * pi);
                }
            } else {
                const int bm = 1 << b;
#pragma unroll
                for (int r = 0; r < 16; ++r) {
                    if (!(r & bm)) {
                        const int r1 = r | bm;
                        float a0r = sr[r], a0i = si[r];
                        float a1r = sr[r1], a1i = si[r1];
                        sr[r]  = fmaf(cy, a0r, -sy * a1r);
                        si[r]  = fmaf(cy, a0i, -sy * a1i);
                        sr[r1] = fmaf(sy, a0r,  cy * a1r);
                        si[r1] = fmaf(sy, a0i,  cy * a1i);
                    }
                }
            }
            // RZ(w1): diag(conj(pz), pz)
            const float tz = 0.5f * wl[q * 2 + 1];
            const float cz = __cosf(tz), sz = __sinf(tz);
            if (b >= 4) {
                const float ss = (lane & (1 << (b - 4))) ? sz : -sz;
#pragma unroll
                for (int r = 0; r < 16; ++r) {
                    float ar = sr[r], ai = si[r];
                    sr[r] = fmaf(cz, ar, -ss * ai);
                    si[r] = fmaf(cz, ai,  ss * ar);
                }
            } else {
#pragma unroll
                for (int r = 0; r < 16; ++r) {
                    const float ss = (r & (1 << b)) ? sz : -sz;
                    float ar = sr[r], ai = si[r];
                    sr[r] = fmaf(cz, ar, -ss * ai);
                    si[r] = fmaf(cz, ai,  ss * ar);
                }
            }
        }

        // ---- ring CNOTs q -> q+1 (mod 10) ----
        // q=0..4: control/target both lane bits -> compose into ONE permutation
        {
            int srcl = lane;
#pragma unroll
            for (int q = 4; q >= 0; --q) {       // reverse application order
                const int bc = 5 - q;            // lane bit of control
                const int bt = bc - 1;           // lane bit of target
                srcl ^= ((srcl >> bc) & 1) << bt;
            }
#pragma unroll
            for (int r = 0; r < 16; ++r) {
                sr[r] = __shfl(sr[r], srcl);
                si[r] = __shfl(si[r], srcl);
            }
        }
        // q=5: control = lane bit0, target = reg bit3 -> in-lane predicated swap
        {
            const bool ctrl = (lane & 1);
#pragma unroll
            for (int r = 0; r < 8; ++r) {
                float t0 = sr[r], t1 = sr[r + 8];
                sr[r]     = ctrl ? t1 : t0;
                sr[r + 8] = ctrl ? t0 : t1;
                t0 = si[r]; t1 = si[r + 8];
                si[r]     = ctrl ? t1 : t0;
                si[r + 8] = ctrl ? t0 : t1;
            }
        }
        // q=6,7,8: both reg bits -> compile-time register permutation
        {
            float tr[16], ti[16];
#pragma unroll
            for (int r = 0; r < 16; ++r) {
                int s0 = r ^ (((r >> 1) & 1) << 0);   // q=8: bc=1 bt=0 (last)
                s0 = s0 ^ (((s0 >> 2) & 1) << 1);     // q=7: bc=2 bt=1
                s0 = s0 ^ (((s0 >> 3) & 1) << 2);     // q=6: bc=3 bt=2 (first)
                tr[r] = sr[s0]; ti[r] = si[s0];
            }
#pragma unroll
            for (int r = 0; r < 16; ++r) { sr[r] = tr[r]; si[r] = ti[r]; }
        }
        // q=9: control = reg bit0, target = lane bit5 -> shfl_xor(32) on odd regs
        {
#pragma unroll
            for (int r = 1; r < 16; r += 2) {
                sr[r] = __shfl_xor(sr[r], 32);
                si[r] = __shfl_xor(si[r], 32);
            }
        }
    }

    // ---------------- measurement: z[q] = sum |a|^2 * (1 - 2*bit_{9-q}) ------
    float P = 0.f, z6 = 0.f, z7 = 0.f, z8 = 0.f, z9 = 0.f;
#pragma unroll
    for (int r = 0; r < 16; ++r) {
        float p = fmaf(sr[r], sr[r], si[r] * si[r]);
        P += p;
        z6 += (r & 8) ? -p : p;
        z7 += (r & 4) ? -p : p;
        z8 += (r & 2) ? -p : p;
        z9 += (r & 1) ? -p : p;
    }
    float z[NQ];
#pragma unroll
    for (int q = 0; q < 6; ++q)
        z[q] = (lane & (1 << (5 - q))) ? -P : P;
    z[6] = z6; z[7] = z7; z[8] = z8; z[9] = z9;
#pragma unroll
    for (int off = 32; off >= 1; off >>= 1) {
#pragma unroll
        for (int q = 0; q < NQ; ++q) z[q] += __shfl_xor(z[q], off);
    }

    // ---------------- epilogue: out = x + z @ out_W^T + out_b ----------------
    float* orow = out + (size_t)tok * DQ;
#pragma unroll
    for (int k = 0; k < 8; ++k) {
        const int d = lane + 64 * k;
        float acc = xv[k] + out_b[d];
#pragma unroll
        for (int q = 0; q < NQ; ++q)
            acc = fmaf(z[q], lds_oW[q * DQ + d], acc);
        orow[d] = acc;
    }
}

extern "C" void kernel_launch(void* const* d_in, const int* in_sizes, int n_in,
                              void* d_out, int out_size, void* d_ws, size_t ws_size,
                              hipStream_t stream) {
    const float* x       = (const float*)d_in[0];
    const float* in_W    = (const float*)d_in[1];
    const float* in_b    = (const float*)d_in[2];
    const float* gamma   = (const float*)d_in[3];
    const float* beta    = (const float*)d_in[4];
    const float* weights = (const float*)d_in[5];
    const float* out_W   = (const float*)d_in[6];
    const float* out_b   = (const float*)d_in[7];
    float* out = (float*)d_out;

    dim3 grid(NTOK / 4), block(256);
    hipLaunchKernelGGL(quantum_kernel, grid, block, 0, stream,
                       x, in_W, in_b, gamma, beta, weights, out_W, out_b, out);
}

// Round 2
// 386.135 us; speedup vs baseline: 1.1200x; 1.1200x over previous
//
#include <hip/hip_runtime.h>

// QuantumLayer: B=8, L=2048, D=512, NQ=10, 4 layers, DIM=1024.
// One wave per token. State packed as float2: amplitude index i (10 bits):
//   lane = i>>4 (bits 9..4), reg r = i&15; r = 2*j + e  (j = vector idx, e = element)
// qubit q sits at bit 9-q:  q0..q5 -> lane bits 5..0; q6 -> r bit3 (j bit2),
// q7 -> r bit2 (j bit1), q8 -> r bit1 (j bit0), q9 -> r bit0 (element).
#define NQ 10
#define DQ 512
#define QL 4
#define NTOK (8 * 2048)

typedef float v2f __attribute__((ext_vector_type(2)));

// ---- cross-lane helpers: DPP for xor 1/2/8, ds for 4/16/32 -----------------
template <int CTRL>
__device__ __forceinline__ float dppf(float v) {
    int i = __builtin_bit_cast(int, v);
    i = __builtin_amdgcn_update_dpp(i, i, CTRL, 0xF, 0xF, false);
    return __builtin_bit_cast(float, i);
}
template <int M>
__device__ __forceinline__ float lx(float v) {
    if constexpr (M == 1)      return dppf<0xB1>(v);   // quad_perm [1,0,3,2]
    else if constexpr (M == 2) return dppf<0x4E>(v);   // quad_perm [2,3,0,1]
    else if constexpr (M == 8) return dppf<0x128>(v);  // row_ror:8 == xor 8
    else return __shfl_xor(v, M);
}
template <int M>
__device__ __forceinline__ v2f lx2(v2f v) {
    v2f r; r.x = lx<M>(v.x); r.y = lx<M>(v.y); return r;
}

__device__ __forceinline__ void reduce10(float* z) {
#pragma unroll
    for (int q = 0; q < NQ; ++q) {
        z[q] += lx<32>(z[q]); z[q] += lx<16>(z[q]); z[q] += lx<8>(z[q]);
        z[q] += lx<4>(z[q]);  z[q] += lx<2>(z[q]);  z[q] += lx<1>(z[q]);
    }
}

// ---- gate kernels ----------------------------------------------------------
template <int M>
__device__ __forceinline__ void rx_lane(v2f* sr2, v2f* si2, float c, float s) {
#pragma unroll
    for (int j = 0; j < 8; ++j) {
        v2f pr = lx2<M>(sr2[j]), pi = lx2<M>(si2[j]);
        sr2[j] = c * sr2[j] + s * pi;
        si2[j] = c * si2[j] - s * pr;
    }
}
template <int BJ>
__device__ __forceinline__ void rx_reg(v2f* sr2, v2f* si2, float c, float s) {
#pragma unroll
    for (int j = 0; j < 8; ++j) if (!(j & BJ)) {
        const int j1 = j | BJ;
        v2f a0r = sr2[j], a0i = si2[j], a1r = sr2[j1], a1i = si2[j1];
        sr2[j]  = c * a0r + s * a1i;
        si2[j]  = c * a0i - s * a1r;
        sr2[j1] = c * a1r + s * a0i;
        si2[j1] = c * a1i - s * a0r;
    }
}
__device__ __forceinline__ void rx_elem(v2f* sr2, v2f* si2, float c, float s) {
#pragma unroll
    for (int j = 0; j < 8; ++j) {
        v2f ar = sr2[j], ai = si2[j];
        v2f swr = {ar.y, ar.x}, swi = {ai.y, ai.x};
        sr2[j] = c * ar + s * swi;
        si2[j] = c * ai - s * swr;
    }
}
template <int M>
__device__ __forceinline__ void ry_lane(v2f* sr2, v2f* si2, float c, float ss) {
#pragma unroll
    for (int j = 0; j < 8; ++j) {
        v2f pr = lx2<M>(sr2[j]), pi = lx2<M>(si2[j]);
        sr2[j] = c * sr2[j] + ss * pr;
        si2[j] = c * si2[j] + ss * pi;
    }
}
template <int BJ>
__device__ __forceinline__ void ry_reg(v2f* sr2, v2f* si2, float c, float s) {
#pragma unroll
    for (int j = 0; j < 8; ++j) if (!(j & BJ)) {
        const int j1 = j | BJ;
        v2f a0r = sr2[j], a0i = si2[j], a1r = sr2[j1], a1i = si2[j1];
        sr2[j]  = c * a0r - s * a1r;
        si2[j]  = c * a0i - s * a1i;
        sr2[j1] = s * a0r + c * a1r;
        si2[j1] = s * a0i + c * a1i;
    }
}
__device__ __forceinline__ void ry_elem(v2f* sr2, v2f* si2, float c, float s) {
#pragma unroll
    for (int j = 0; j < 8; ++j) {
        v2f ar = sr2[j], ai = si2[j];
        sr2[j] = (v2f){c * ar.x - s * ar.y, s * ar.x + c * ar.y};
        si2[j] = (v2f){c * ai.x - s * ai.y, s * ai.x + c * ai.y};
    }
}

// Composed 10-qubit diagonal: per-amp factor = prod_q (c_q + i*(+-s_q)),
// sign + where bit of qubit q is set. Lane part built once; reg part walked
// in Gray order with double-angle ratio updates.
__device__ __forceinline__ void apply_diag(v2f* sr2, v2f* si2,
                                           const float* c, const float* s,
                                           int lane) {
    float Lr, Li;
    {
        float s0 = (lane & 32) ? s[0] : -s[0];
        Lr = c[0]; Li = s0;
#pragma unroll
        for (int q = 1; q < 6; ++q) {
            float sq = (lane & (1 << (5 - q))) ? s[q] : -s[q];
            float nr = Lr * c[q] - Li * sq;
            float ni = Lr * sq + Li * c[q];
            Lr = nr; Li = ni;
        }
    }
    // G(j=0) = conj(f6)*conj(f7)*conj(f8)
    float Gr, Gi;
    {
        float pr = c[6] * c[7] - s[6] * s[7];
        float pi = -(c[6] * s[7] + s[6] * c[7]);
        Gr = pr * c[8] + pi * s[8];
        Gi = -pr * s[8] + pi * c[8];
    }
    const float R6r = c[6]*c[6] - s[6]*s[6], R6i = 2.f*c[6]*s[6];
    const float R7r = c[7]*c[7] - s[7]*s[7], R7i = 2.f*c[7]*s[7];
    const float R8r = c[8]*c[8] - s[8]*s[8], R8i = 2.f*c[8]*s[8];
    const float c9 = c[9];
    const v2f Ki = {-s[9], s[9]};

    auto app = [&](int j) {
        float Mr = Lr * Gr - Li * Gi;
        float Mi = Lr * Gi + Li * Gr;
        v2f Fr = Mr * c9 - Mi * Ki;
        v2f Fi = Mr * Ki + Mi * c9;
        v2f ar = sr2[j], ai = si2[j];
        sr2[j] = ar * Fr - ai * Fi;
        si2[j] = ar * Fi + ai * Fr;
    };
    auto gmul = [&](float rr, float ri) {
        float nr = Gr * rr - Gi * ri;
        float ni = Gr * ri + Gi * rr;
        Gr = nr; Gi = ni;
    };
    app(0);
    gmul(R8r,  R8i); app(1);
    gmul(R7r,  R7i); app(3);
    gmul(R8r, -R8i); app(2);
    gmul(R6r,  R6i); app(6);
    gmul(R8r,  R8i); app(7);
    gmul(R7r, -R7i); app(5);
    gmul(R8r, -R8i); app(4);
}

__global__ __launch_bounds__(256, 5) void quantum_kernel(
    const float* __restrict__ x, const float* __restrict__ in_W,
    const float* __restrict__ in_b, const float* __restrict__ gamma,
    const float* __restrict__ beta, const float* __restrict__ weights,
    const float* __restrict__ out_W, const float* __restrict__ out_b,
    float* __restrict__ out)
{
    __shared__ float lds_oW[NQ * DQ];   // out_W transposed: [q][d]
    const int t = threadIdx.x;
    for (int idx = t; idx < NQ * DQ; idx += 256) {
        int d = idx / NQ;
        int q = idx - d * NQ;
        lds_oW[q * DQ + d] = out_W[idx];
    }
    __syncthreads();

    const int lane = t & 63;
    const int tok = blockIdx.x * 4 + (t >> 6);

    // ---------------- stage 1: h = tanh(x @ in_W^T + in_b), then LN ----------
    const float* xrow = x + (size_t)tok * DQ;
    float h[NQ];
#pragma unroll
    for (int q = 0; q < NQ; ++q) h[q] = 0.f;
#pragma unroll
    for (int k = 0; k < 8; ++k) {
        float xk = xrow[lane + 64 * k];
#pragma unroll
        for (int q = 0; q < NQ; ++q)
            h[q] = fmaf(xk, in_W[q * DQ + lane + 64 * k], h[q]);
    }
    reduce10(h);

    float mu = 0.f;
#pragma unroll
    for (int q = 0; q < NQ; ++q) {
        float e = __expf(2.f * (h[q] + in_b[q]));
        h[q] = (e - 1.f) * __builtin_amdgcn_rcpf(e + 1.f);
        mu += h[q];
    }
    mu *= 0.1f;
    float var = 0.f;
#pragma unroll
    for (int q = 0; q < NQ; ++q) { float d0 = h[q] - mu; var += d0 * d0; }
    var *= 0.1f;
    const float rstd = rsqrtf(var + 1e-5f);

    float cq[NQ], sq[NQ];
#pragma unroll
    for (int q = 0; q < NQ; ++q) {
        float f = (h[q] - mu) * rstd * gamma[q] + beta[q];
        float hf = 0.5f * f;
        cq[q] = __cosf(hf);
        sq[q] = __sinf(hf);
    }

    // ---------------- statevector init: |0...0> ------------------------------
    v2f sr2[8], si2[8];
#pragma unroll
    for (int j = 0; j < 8; ++j) { sr2[j] = (v2f){0.f, 0.f}; si2[j] = (v2f){0.f, 0.f}; }
    if (lane == 0) sr2[0].x = 1.f;

    // ---------------- circuit -------------------------------------------------
#pragma unroll 1
    for (int l = 0; l < QL; ++l) {
        // ---- RX(feats[q]) on all 10 qubits ----
        rx_lane<32>(sr2, si2, cq[0], sq[0]);
        rx_lane<16>(sr2, si2, cq[1], sq[1]);
        rx_lane< 8>(sr2, si2, cq[2], sq[2]);
        rx_lane< 4>(sr2, si2, cq[3], sq[3]);
        rx_lane< 2>(sr2, si2, cq[4], sq[4]);
        rx_lane< 1>(sr2, si2, cq[5], sq[5]);
        rx_reg<4>(sr2, si2, cq[6], sq[6]);
        rx_reg<2>(sr2, si2, cq[7], sq[7]);
        rx_reg<1>(sr2, si2, cq[8], sq[8]);
        rx_elem(sr2, si2, cq[9], sq[9]);

        // ---- token phase block: one composed diagonal ----
        apply_diag(sr2, si2, cq, sq, lane);

        // ---- RY(w0) on all 10 qubits (RZs commuted to after the block) ----
        const float* wl = weights + l * NQ * 2;
        { float a = 0.5f*wl[ 0]; float cy=__cosf(a), sy=__sinf(a); ry_lane<32>(sr2,si2,cy,(lane&32)?sy:-sy); }
        { float a = 0.5f*wl[ 2]; float cy=__cosf(a), sy=__sinf(a); ry_lane<16>(sr2,si2,cy,(lane&16)?sy:-sy); }
        { float a = 0.5f*wl[ 4]; float cy=__cosf(a), sy=__sinf(a); ry_lane< 8>(sr2,si2,cy,(lane& 8)?sy:-sy); }
        { float a = 0.5f*wl[ 6]; float cy=__cosf(a), sy=__sinf(a); ry_lane< 4>(sr2,si2,cy,(lane& 4)?sy:-sy); }
        { float a = 0.5f*wl[ 8]; float cy=__cosf(a), sy=__sinf(a); ry_lane< 2>(sr2,si2,cy,(lane& 2)?sy:-sy); }
        { float a = 0.5f*wl[10]; float cy=__cosf(a), sy=__sinf(a); ry_lane< 1>(sr2,si2,cy,(lane& 1)?sy:-sy); }
        { float a = 0.5f*wl[12]; ry_reg<4>(sr2, si2, __cosf(a), __sinf(a)); }
        { float a = 0.5f*wl[14]; ry_reg<2>(sr2, si2, __cosf(a), __sinf(a)); }
        { float a = 0.5f*wl[16]; ry_reg<1>(sr2, si2, __cosf(a), __sinf(a)); }
        { float a = 0.5f*wl[18]; ry_elem(sr2, si2, __cosf(a), __sinf(a)); }

        // ---- RZ(w1) block: one composed diagonal ----
        {
            float cz[NQ], sz[NQ];
#pragma unroll
            for (int q = 0; q < NQ; ++q) {
                float a = 0.5f * wl[2 * q + 1];
                cz[q] = __cosf(a); sz[q] = __sinf(a);
            }
            apply_diag(sr2, si2, cz, sz, lane);
        }

        // ---- ring CNOTs q -> q+1 (mod 10) ----
        // q=0..4: all lane bits -> one composed lane permutation
        {
            int srcl = lane;
#pragma unroll
            for (int q = 4; q >= 0; --q) {
                const int bc = 5 - q, bt = bc - 1;
                srcl ^= ((srcl >> bc) & 1) << bt;
            }
#pragma unroll
            for (int j = 0; j < 8; ++j) {
                sr2[j].x = __shfl(sr2[j].x, srcl); sr2[j].y = __shfl(sr2[j].y, srcl);
                si2[j].x = __shfl(si2[j].x, srcl); si2[j].y = __shfl(si2[j].y, srcl);
            }
        }
        // q=5: control = lane bit0, target = r bit3 (j bit2)
        {
            const bool ctrl = (lane & 1);
#pragma unroll
            for (int j = 0; j < 4; ++j) {
                v2f t0 = sr2[j], t1 = sr2[j + 4];
                sr2[j]     = ctrl ? t1 : t0;
                sr2[j + 4] = ctrl ? t0 : t1;
                t0 = si2[j]; t1 = si2[j + 4];
                si2[j]     = ctrl ? t1 : t0;
                si2[j + 4] = ctrl ? t0 : t1;
            }
        }
        // q=6,7,8: static register permutation
        {
            float tr[16], ti[16];
#pragma unroll
            for (int r = 0; r < 16; ++r) {
                int s0 = r ^ ((r >> 1) & 1);
                s0 ^= ((s0 >> 2) & 1) << 1;
                s0 ^= ((s0 >> 3) & 1) << 2;
                tr[r] = (s0 & 1) ? sr2[s0 >> 1].y : sr2[s0 >> 1].x;
                ti[r] = (s0 & 1) ? si2[s0 >> 1].y : si2[s0 >> 1].x;
            }
#pragma unroll
            for (int j = 0; j < 8; ++j) {
                sr2[j] = (v2f){tr[2 * j], tr[2 * j + 1]};
                si2[j] = (v2f){ti[2 * j], ti[2 * j + 1]};
            }
        }
        // q=9: control = r bit0 (element 1), target = lane bit5
#pragma unroll
        for (int j = 0; j < 8; ++j) {
            sr2[j].y = __shfl_xor(sr2[j].y, 32);
            si2[j].y = __shfl_xor(si2[j].y, 32);
        }
    }

    // ---------------- measurement -------------------------------------------
    v2f aP = {0.f, 0.f}, a6 = {0.f, 0.f}, a7 = {0.f, 0.f}, a8 = {0.f, 0.f};
#pragma unroll
    for (int j = 0; j < 8; ++j) {
        v2f p = sr2[j] * sr2[j] + si2[j] * si2[j];
        aP += p;
        if (j & 4) a6 -= p; else a6 += p;
        if (j & 2) a7 -= p; else a7 += p;
        if (j & 1) a8 -= p; else a8 += p;
    }
    const float P = aP.x + aP.y;
    float z[NQ];
#pragma unroll
    for (int q = 0; q < 6; ++q)
        z[q] = (lane & (1 << (5 - q))) ? -P : P;
    z[6] = a6.x + a6.y; z[7] = a7.x + a7.y; z[8] = a8.x + a8.y;
    z[9] = aP.x - aP.y;
    reduce10(z);

    // ---------------- epilogue: out = x + z @ out_W^T + out_b ----------------
    float* orow = out + (size_t)tok * DQ;
#pragma unroll
    for (int k = 0; k < 8; ++k) {
        const int d = lane + 64 * k;
        float acc = xrow[d] + out_b[d];
#pragma unroll
        for (int q = 0; q < NQ; ++q)
            acc = fmaf(z[q], lds_oW[q * DQ + d], acc);
        orow[d] = acc;
    }
}

extern "C" void kernel_launch(void* const* d_in, const int* in_sizes, int n_in,
                              void* d_out, int out_size, void* d_ws, size_t ws_size,
                              hipStream_t stream) {
    const float* x       = (const float*)d_in[0];
    const float* in_W    = (const float*)d_in[1];
    const float* in_b    = (const float*)d_in[2];
    const float* gamma   = (const float*)d_in[3];
    const float* beta    = (const float*)d_in[4];
    const float* weights = (const float*)d_in[5];
    const float* out_W   = (const float*)d_in[6];
    const float* out_b   = (const float*)d_in[7];
    float* out = (float*)d_out;

    dim3 grid(NTOK / 4), block(256);
    hipLaunchKernelGGL(quantum_kernel, grid, block, 0, stream,
                       x, in_W, in_b, gamma, beta, weights, out_W, out_b, out);
}

// Round 4
// 327.709 us; speedup vs baseline: 1.3197x; 1.1783x over previous
//
#include <hip/hip_runtime.h>

// QuantumLayer: B=8, L=2048, D=512, NQ=10, 4 layers, DIM=1024.
// One wave per token. State packed as float2: amplitude index i (10 bits):
//   lane = i>>4 (bits 9..4), reg r = i&15; r = 2*j + e (j = v2f idx, e = elem)
// qubit q sits at bit 9-q: q0..q5 -> lane bits 5..0; q6 -> j bit2,
// q7 -> j bit1, q8 -> j bit0, q9 -> element.
#define NQ 10
#define DQ 512
#define QL 4
#define NTOK (8 * 2048)

typedef float v2f __attribute__((ext_vector_type(2)));

// ---- cross-lane xor-M: DPP for 1/2/8 (proven R2), __shfl_xor for 4/16/32 ---
template <int CTRL>
__device__ __forceinline__ float dppf(float v) {
    int i = __builtin_bit_cast(int, v);
    i = __builtin_amdgcn_update_dpp(i, i, CTRL, 0xF, 0xF, false);
    return __builtin_bit_cast(float, i);
}
template <int M>
__device__ __forceinline__ float lx(float v) {
    if constexpr (M == 1)      return dppf<0xB1>(v);   // quad_perm [1,0,3,2]
    else if constexpr (M == 2) return dppf<0x4E>(v);   // quad_perm [2,3,0,1]
    else if constexpr (M == 8) return dppf<0x128>(v);  // row_ror:8 == xor 8
    else return __shfl_xor(v, M);
}
template <int M>
__device__ __forceinline__ v2f lx2(v2f v) {
    v2f r; r.x = lx<M>(v.x); r.y = lx<M>(v.y); return r;
}

__device__ __forceinline__ void reduce10(float* z) {
#pragma unroll
    for (int q = 0; q < NQ; ++q) {
        z[q] += lx<32>(z[q]); z[q] += lx<16>(z[q]); z[q] += lx<8>(z[q]);
        z[q] += lx<4>(z[q]);  z[q] += lx<2>(z[q]);  z[q] += lx<1>(z[q]);
    }
}

// ---- gate kernels ----------------------------------------------------------
template <int M>
__device__ __forceinline__ void rx_lane(v2f* sr2, v2f* si2, float c, float s) {
#pragma unroll
    for (int j = 0; j < 8; ++j) {
        v2f pr = lx2<M>(sr2[j]), pi = lx2<M>(si2[j]);
        sr2[j] = c * sr2[j] + s * pi;
        si2[j] = c * si2[j] - s * pr;
    }
}
template <int BJ>
__device__ __forceinline__ void rx_reg(v2f* sr2, v2f* si2, float c, float s) {
#pragma unroll
    for (int j = 0; j < 8; ++j) if (!(j & BJ)) {
        const int j1 = j | BJ;
        v2f a0r = sr2[j], a0i = si2[j], a1r = sr2[j1], a1i = si2[j1];
        sr2[j]  = c * a0r + s * a1i;
        si2[j]  = c * a0i - s * a1r;
        sr2[j1] = c * a1r + s * a0i;
        si2[j1] = c * a1i - s * a0r;
    }
}
__device__ __forceinline__ void rx_elem(v2f* sr2, v2f* si2, float c, float s) {
#pragma unroll
    for (int j = 0; j < 8; ++j) {
        v2f ar = sr2[j], ai = si2[j];
        v2f swr = {ar.y, ar.x}, swi = {ai.y, ai.x};
        sr2[j] = c * ar + s * swi;
        si2[j] = c * ai - s * swr;
    }
}
template <int M>
__device__ __forceinline__ void ry_lane(v2f* sr2, v2f* si2, float c, float ss) {
#pragma unroll
    for (int j = 0; j < 8; ++j) {
        v2f pr = lx2<M>(sr2[j]), pi = lx2<M>(si2[j]);
        sr2[j] = c * sr2[j] + ss * pr;
        si2[j] = c * si2[j] + ss * pi;
    }
}
template <int BJ>
__device__ __forceinline__ void ry_reg(v2f* sr2, v2f* si2, float c, float s) {
#pragma unroll
    for (int j = 0; j < 8; ++j) if (!(j & BJ)) {
        const int j1 = j | BJ;
        v2f a0r = sr2[j], a0i = si2[j], a1r = sr2[j1], a1i = si2[j1];
        sr2[j]  = c * a0r - s * a1r;
        si2[j]  = c * a0i - s * a1i;
        sr2[j1] = s * a0r + c * a1r;
        si2[j1] = s * a0i + c * a1i;
    }
}
__device__ __forceinline__ void ry_elem(v2f* sr2, v2f* si2, float c, float s) {
#pragma unroll
    for (int j = 0; j < 8; ++j) {
        v2f ar = sr2[j], ai = si2[j];
        sr2[j] = (v2f){c * ar.x - s * ar.y, s * ar.x + c * ar.y};
        si2[j] = (v2f){c * ai.x - s * ai.y, s * ai.x + c * ai.y};
    }
}

// Composed 10-qubit diagonal. Lane factor built once; reg factor walked in
// Gray order over j (q6,q7,q8) with double-angle ratio updates; q9 element
// pair folded into a packed factor.
__device__ __forceinline__ void apply_diag(v2f* sr2, v2f* si2,
                                           const float* c, const float* s,
                                           int lane) {
    float Lr, Li;
    {
        float s0 = (lane & 32) ? s[0] : -s[0];
        Lr = c[0]; Li = s0;
#pragma unroll
        for (int q = 1; q < 6; ++q) {
            float sq = (lane & (1 << (5 - q))) ? s[q] : -s[q];
            float nr = Lr * c[q] - Li * sq;
            float ni = Lr * sq + Li * c[q];
            Lr = nr; Li = ni;
        }
    }
    float Gr, Gi;
    {
        float pr = c[6] * c[7] - s[6] * s[7];
        float pi = -(c[6] * s[7] + s[6] * c[7]);
        Gr = pr * c[8] + pi * s[8];
        Gi = -pr * s[8] + pi * c[8];
    }
    const float R6r = c[6]*c[6] - s[6]*s[6], R6i = 2.f*c[6]*s[6];
    const float R7r = c[7]*c[7] - s[7]*s[7], R7i = 2.f*c[7]*s[7];
    const float R8r = c[8]*c[8] - s[8]*s[8], R8i = 2.f*c[8]*s[8];
    const float c9 = c[9];
    const v2f Ki = {-s[9], s[9]};

    auto app = [&](int j) {
        float Mr = Lr * Gr - Li * Gi;
        float Mi = Lr * Gi + Li * Gr;
        v2f Fr = Mr * c9 - Mi * Ki;
        v2f Fi = Mr * Ki + Mi * c9;
        v2f ar = sr2[j], ai = si2[j];
        sr2[j] = ar * Fr - ai * Fi;
        si2[j] = ar * Fi + ai * Fr;
    };
    auto gmul = [&](float rr, float ri) {
        float nr = Gr * rr - Gi * ri;
        float ni = Gr * ri + Gi * rr;
        Gr = nr; Gi = ni;
    };
    app(0);
    gmul(R8r,  R8i); app(1);
    gmul(R7r,  R7i); app(3);
    gmul(R8r, -R8i); app(2);
    gmul(R6r,  R6i); app(6);
    gmul(R8r,  R8i); app(7);
    gmul(R7r, -R7i); app(5);
    gmul(R8r, -R8i); app(4);
}

// CNOT q=6,7,8 composed register permutation, cycle form (1 temp per cycle):
// dest<-src: (2 3), (4<-6<-5<-7<-4), (8<-12<-10<-15<-8), (9<-13<-11<-14<-9)
__device__ __forceinline__ void perm678(v2f* a) {
    float t;
    t = a[1].x; a[1].x = a[1].y; a[1].y = t;
    t = a[2].x; a[2].x = a[3].x; a[3].x = a[2].y; a[2].y = a[3].y; a[3].y = t;
    t = a[4].x; a[4].x = a[6].x; a[6].x = a[5].x; a[5].x = a[7].y; a[7].y = t;
    t = a[4].y; a[4].y = a[6].y; a[6].y = a[5].y; a[5].y = a[7].x; a[7].x = t;
}

__global__ __launch_bounds__(256) void quantum_kernel(
    const float* __restrict__ x, const float* __restrict__ in_W,
    const float* __restrict__ in_b, const float* __restrict__ gamma,
    const float* __restrict__ beta, const float* __restrict__ weights,
    const float* __restrict__ out_W, const float* __restrict__ out_b,
    float* __restrict__ out)
{
    __shared__ v2f lds_oW2[NQ * (DQ / 2)];   // out_W transposed: [q][d]
    float* lds_f = (float*)lds_oW2;
    const int t = threadIdx.x;
    // stage out_W^T without integer division: 2 chunks of 256 d-values
#pragma unroll
    for (int rep = 0; rep < 2; ++rep) {
        const int d = t + rep * 256;
#pragma unroll
        for (int q = 0; q < NQ; ++q)
            lds_f[q * DQ + d] = out_W[d * NQ + q];
    }
    __syncthreads();

    const int lane = t & 63;
    const int tok = blockIdx.x * 4 + (t >> 6);

    // composed CNOT lane permutation (q0..4) source lane, hoisted
    int srcl = lane;
#pragma unroll
    for (int q = 4; q >= 0; --q) {
        const int bc = 5 - q, bt = bc - 1;
        srcl ^= ((srcl >> bc) & 1) << bt;
    }

    // ---------------- stage 1: h = tanh(x @ in_W^T + in_b), then LN ----------
    const v2f* xrow2 = (const v2f*)(x + (size_t)tok * DQ);
    const v2f* inW2 = (const v2f*)in_W;
    v2f hv[NQ];
#pragma unroll
    for (int q = 0; q < NQ; ++q) hv[q] = (v2f){0.f, 0.f};
#pragma unroll
    for (int k = 0; k < 4; ++k) {
        v2f xk = xrow2[lane + 64 * k];
#pragma unroll
        for (int q = 0; q < NQ; ++q)
            hv[q] = xk * inW2[q * (DQ / 2) + lane + 64 * k] + hv[q];
    }
    float h[NQ];
#pragma unroll
    for (int q = 0; q < NQ; ++q) h[q] = hv[q].x + hv[q].y;
    reduce10(h);

    float mu = 0.f;
#pragma unroll
    for (int q = 0; q < NQ; ++q) {
        float e = __expf(2.f * (h[q] + in_b[q]));
        h[q] = (e - 1.f) * __builtin_amdgcn_rcpf(e + 1.f);
        mu += h[q];
    }
    mu *= 0.1f;
    float var = 0.f;
#pragma unroll
    for (int q = 0; q < NQ; ++q) { float d0 = h[q] - mu; var += d0 * d0; }
    var *= 0.1f;
    const float rstd = rsqrtf(var + 1e-5f);

    float cq[NQ], sq[NQ];
#pragma unroll
    for (int q = 0; q < NQ; ++q) {
        float f = (h[q] - mu) * rstd * gamma[q] + beta[q];
        float hf = 0.5f * f;
        cq[q] = __cosf(hf);
        sq[q] = __sinf(hf);
    }

    // ---------------- statevector init: |0...0> ------------------------------
    v2f sr2[8], si2[8];
#pragma unroll
    for (int j = 0; j < 8; ++j) { sr2[j] = (v2f){0.f, 0.f}; si2[j] = (v2f){0.f, 0.f}; }
    if (lane == 0) sr2[0].x = 1.f;

    // ---------------- circuit -------------------------------------------------
#pragma unroll 1
    for (int l = 0; l < QL; ++l) {
        // ---- RX(feats[q]) on all 10 qubits ----
        rx_lane<32>(sr2, si2, cq[0], sq[0]);
        rx_lane<16>(sr2, si2, cq[1], sq[1]);
        rx_lane< 8>(sr2, si2, cq[2], sq[2]);
        rx_lane< 4>(sr2, si2, cq[3], sq[3]);
        rx_lane< 2>(sr2, si2, cq[4], sq[4]);
        rx_lane< 1>(sr2, si2, cq[5], sq[5]);
        rx_reg<4>(sr2, si2, cq[6], sq[6]);
        rx_reg<2>(sr2, si2, cq[7], sq[7]);
        rx_reg<1>(sr2, si2, cq[8], sq[8]);
        rx_elem(sr2, si2, cq[9], sq[9]);

        // ---- token phase block: one composed diagonal ----
        apply_diag(sr2, si2, cq, sq, lane);

        // ---- RY(w0) on all 10 qubits ----
        const float* wl = weights + l * NQ * 2;
        { float a = 0.5f*wl[ 0]; float cy=__cosf(a), sy=__sinf(a); ry_lane<32>(sr2,si2,cy,(lane&32)?sy:-sy); }
        { float a = 0.5f*wl[ 2]; float cy=__cosf(a), sy=__sinf(a); ry_lane<16>(sr2,si2,cy,(lane&16)?sy:-sy); }
        { float a = 0.5f*wl[ 4]; float cy=__cosf(a), sy=__sinf(a); ry_lane< 8>(sr2,si2,cy,(lane& 8)?sy:-sy); }
        { float a = 0.5f*wl[ 6]; float cy=__cosf(a), sy=__sinf(a); ry_lane< 4>(sr2,si2,cy,(lane& 4)?sy:-sy); }
        { float a = 0.5f*wl[ 8]; float cy=__cosf(a), sy=__sinf(a); ry_lane< 2>(sr2,si2,cy,(lane& 2)?sy:-sy); }
        { float a = 0.5f*wl[10]; float cy=__cosf(a), sy=__sinf(a); ry_lane< 1>(sr2,si2,cy,(lane& 1)?sy:-sy); }
        { float a = 0.5f*wl[12]; ry_reg<4>(sr2, si2, __cosf(a), __sinf(a)); }
        { float a = 0.5f*wl[14]; ry_reg<2>(sr2, si2, __cosf(a), __sinf(a)); }
        { float a = 0.5f*wl[16]; ry_reg<1>(sr2, si2, __cosf(a), __sinf(a)); }
        { float a = 0.5f*wl[18]; ry_elem(sr2, si2, __cosf(a), __sinf(a)); }

        // ---- RZ(w1) block: one composed diagonal ----
        {
            float cz[NQ], sz[NQ];
#pragma unroll
            for (int q = 0; q < NQ; ++q) {
                float a = 0.5f * wl[2 * q + 1];
                cz[q] = __cosf(a); sz[q] = __sinf(a);
            }
            apply_diag(sr2, si2, cz, sz, lane);
        }

        // ---- ring CNOTs q -> q+1 (mod 10) ----
        // q=0..4: one composed lane permutation (hoisted source lane)
#pragma unroll
        for (int j = 0; j < 8; ++j) {
            sr2[j].x = __shfl(sr2[j].x, srcl); sr2[j].y = __shfl(sr2[j].y, srcl);
            si2[j].x = __shfl(si2[j].x, srcl); si2[j].y = __shfl(si2[j].y, srcl);
        }
        // q=5: control = lane bit0, target = j bit2
        {
            const bool ctrl = (lane & 1);
#pragma unroll
            for (int j = 0; j < 4; ++j) {
                v2f t0 = sr2[j], t1 = sr2[j + 4];
                sr2[j]     = ctrl ? t1 : t0;
                sr2[j + 4] = ctrl ? t0 : t1;
                t0 = si2[j]; t1 = si2[j + 4];
                si2[j]     = ctrl ? t1 : t0;
                si2[j + 4] = ctrl ? t0 : t1;
            }
        }
        // q=6,7,8: in-place cycle permutation (no 32-temp spike)
        perm678(sr2);
        perm678(si2);
        // q=9: control = element bit, target = lane bit5
#pragma unroll
        for (int j = 0; j < 8; ++j) {
            sr2[j].y = __shfl_xor(sr2[j].y, 32);
            si2[j].y = __shfl_xor(si2[j].y, 32);
        }
    }

    // ---------------- measurement -------------------------------------------
    v2f aP = {0.f, 0.f}, a6 = {0.f, 0.f}, a7 = {0.f, 0.f}, a8 = {0.f, 0.f};
#pragma unroll
    for (int j = 0; j < 8; ++j) {
        v2f p = sr2[j] * sr2[j] + si2[j] * si2[j];
        aP += p;
        if (j & 4) a6 -= p; else a6 += p;
        if (j & 2) a7 -= p; else a7 += p;
        if (j & 1) a8 -= p; else a8 += p;
    }
    const float P = aP.x + aP.y;
    float z[NQ];
#pragma unroll
    for (int q = 0; q < 6; ++q)
        z[q] = (lane & (1 << (5 - q))) ? -P : P;
    z[6] = a6.x + a6.y; z[7] = a7.x + a7.y; z[8] = a8.x + a8.y;
    z[9] = aP.x - aP.y;
    reduce10(z);

    // ---------------- epilogue: out = x + z @ out_W^T + out_b ----------------
    v2f* orow2 = (v2f*)(out + (size_t)tok * DQ);
    const v2f* ob2 = (const v2f*)out_b;
#pragma unroll
    for (int k = 0; k < 4; ++k) {
        const int d2 = lane + 64 * k;
        v2f acc = xrow2[d2] + ob2[d2];
#pragma unroll
        for (int q = 0; q < NQ; ++q)
            acc = z[q] * lds_oW2[q * (DQ / 2) + d2] + acc;
        orow2[d2] = acc;
    }
}

extern "C" void kernel_launch(void* const* d_in, const int* in_sizes, int n_in,
                              void* d_out, int out_size, void* d_ws, size_t ws_size,
                              hipStream_t stream) {
    const float* x       = (const float*)d_in[0];
    const float* in_W    = (const float*)d_in[1];
    const float* in_b    = (const float*)d_in[2];
    const float* gamma   = (const float*)d_in[3];
    const float* beta    = (const float*)d_in[4];
    const float* weights = (const float*)d_in[5];
    const float* out_W   = (const float*)d_in[6];
    const float* out_b   = (const float*)d_in[7];
    float* out = (float*)d_out;

    dim3 grid(NTOK / 4), block(256);
    hipLaunchKernelGGL(quantum_kernel, grid, block, 0, stream,
                       x, in_W, in_b, gamma, beta, weights, out_W, out_b, out);
}

// Round 5
// 231.047 us; speedup vs baseline: 1.8719x; 1.4184x over previous
//
#include <hip/hip_runtime.h>

// QuantumLayer: B=8, L=2048, D=512, NQ=10, 4 layers, DIM=1024.
// One wave per token. State packed as float2: amplitude index i (10 bits):
//   lane = i>>4 (bits 9..4), reg r = i&15; r = 2*j + e (j = v2f idx, e = elem)
// qubit q sits at bit 9-q: q0..q5 -> lane bits 5..0; q6 -> j bit2,
// q7 -> j bit1, q8 -> j bit0, q9 -> element.
//
// Per layer, per qubit the reference applies RX(f) -> phase(f) -> RY(w0) ->
// RZ(w1); these compose into one SU(2) gate U = [[a,-conj b],[b,conj a]] with
// (ar,ai,br,bi) = Q0 + A*Q1 + C*Q2, A = c^2, C = c*s (c,s = cos/sin(f/2)),
// Q* weight-only constants precomputed once per block into LDS.
// Layer 1 acts on |0..0>: its single-qubit stage yields a product state built
// directly by outer product (no gate passes).
#define NQ 10
#define DQ 512
#define QL 4
#define NTOK (8 * 2048)

typedef float v2f __attribute__((ext_vector_type(2)));
typedef float v4f __attribute__((ext_vector_type(4)));

// ---- cross-lane xor-M: DPP for 1/2/8, __shfl_xor for 4/16/32 (R4-proven) ---
template <int CTRL>
__device__ __forceinline__ float dppf(float v) {
    int i = __builtin_bit_cast(int, v);
    i = __builtin_amdgcn_update_dpp(i, i, CTRL, 0xF, 0xF, false);
    return __builtin_bit_cast(float, i);
}
template <int M>
__device__ __forceinline__ float lx(float v) {
    if constexpr (M == 1)      return dppf<0xB1>(v);   // quad_perm [1,0,3,2]
    else if constexpr (M == 2) return dppf<0x4E>(v);   // quad_perm [2,3,0,1]
    else if constexpr (M == 8) return dppf<0x128>(v);  // row_ror:8 == xor 8
    else return __shfl_xor(v, M);
}
template <int M>
__device__ __forceinline__ v2f lx2(v2f v) {
    v2f r; r.x = lx<M>(v.x); r.y = lx<M>(v.y); return r;
}

__device__ __forceinline__ void reduce10(float* z) {
#pragma unroll
    for (int q = 0; q < NQ; ++q) {
        z[q] += lx<32>(z[q]); z[q] += lx<16>(z[q]); z[q] += lx<8>(z[q]);
        z[q] += lx<4>(z[q]);  z[q] += lx<2>(z[q]);  z[q] += lx<1>(z[q]);
    }
}

// coef = Q0 + A*Q1 + C*Q2  ->  (ar, ai, br, bi)
__device__ __forceinline__ v4f coef(const v4f* Q, float c, float s) {
    float A = c * c, C = c * s;
    return Q[0] + A * Q[1] + C * Q[2];
}

// ---- general SU(2) gate on a lane-bit qubit --------------------------------
// own coeff: (ar, +-ai); partner coeff: (-+br, bi)  [sign by own bit]
template <int M>
__device__ __forceinline__ void gate_lane(v2f* sr2, v2f* si2, v4f cf, bool bit) {
    const float ar = cf.x;
    const float Ai = bit ? -cf.y : cf.y;
    const float Br = bit ? cf.z : -cf.z;
    const float bi = cf.w;
#pragma unroll
    for (int j = 0; j < 8; ++j) {
        v2f wr = lx2<M>(sr2[j]), wi = lx2<M>(si2[j]);
        v2f nr = ar * sr2[j] - Ai * si2[j] + Br * wr - bi * wi;
        v2f ni = ar * si2[j] + Ai * sr2[j] + Br * wi + bi * wr;
        sr2[j] = nr; si2[j] = ni;
    }
}
template <int BJ>
__device__ __forceinline__ void gate_reg(v2f* sr2, v2f* si2, v4f cf) {
    const float ar = cf.x, ai = cf.y, br = cf.z, bi = cf.w;
#pragma unroll
    for (int j = 0; j < 8; ++j) if (!(j & BJ)) {
        const int j1 = j | BJ;
        v2f x0r = sr2[j], x0i = si2[j], x1r = sr2[j1], x1i = si2[j1];
        sr2[j]  = ar * x0r - ai * x0i - br * x1r - bi * x1i;
        si2[j]  = ar * x0i + ai * x0r - br * x1i + bi * x1r;
        sr2[j1] = br * x0r - bi * x0i + ar * x1r + ai * x1i;
        si2[j1] = br * x0i + bi * x0r + ar * x1i - ai * x1r;
    }
}
__device__ __forceinline__ void gate_elem(v2f* sr2, v2f* si2, v4f cf) {
    const float ar = cf.x, ai = cf.y, br = cf.z, bi = cf.w;
    const v2f cA = {ar, br}, cB = {-ai, -bi}, cC = {-br, ar}, cD = {-bi, ai};
    const v2f cF = {ai, bi}, cH = {bi, -ai};
#pragma unroll
    for (int j = 0; j < 8; ++j) {
        float x0r = sr2[j].x, x0i = si2[j].x, x1r = sr2[j].y, x1i = si2[j].y;
        v2f nr = x0r * cA + x0i * cB + x1r * cC + x1i * cD;
        v2f ni = x0i * cA + x0r * cF + x1i * cC + x1r * cH;
        sr2[j] = nr; si2[j] = ni;
    }
}

// CNOT q=6,7,8 composed register permutation, cycle form (R4-proven)
__device__ __forceinline__ void perm678(v2f* a) {
    float t;
    t = a[1].x; a[1].x = a[1].y; a[1].y = t;
    t = a[2].x; a[2].x = a[3].x; a[3].x = a[2].y; a[2].y = a[3].y; a[3].y = t;
    t = a[4].x; a[4].x = a[6].x; a[6].x = a[5].x; a[5].x = a[7].y; a[7].y = t;
    t = a[4].y; a[4].y = a[6].y; a[6].y = a[5].y; a[5].y = a[7].x; a[7].x = t;
}

// ring CNOTs q -> q+1 (mod 10) (R4-proven structure)
__device__ __forceinline__ void cnot_ring(v2f* sr2, v2f* si2, int lane, int srcl) {
    // q=0..4: one composed lane permutation
#pragma unroll
    for (int j = 0; j < 8; ++j) {
        sr2[j].x = __shfl(sr2[j].x, srcl); sr2[j].y = __shfl(sr2[j].y, srcl);
        si2[j].x = __shfl(si2[j].x, srcl); si2[j].y = __shfl(si2[j].y, srcl);
    }
    // q=5: control = lane bit0, target = j bit2
    {
        const bool ctrl = (lane & 1);
#pragma unroll
        for (int j = 0; j < 4; ++j) {
            v2f t0 = sr2[j], t1 = sr2[j + 4];
            sr2[j]     = ctrl ? t1 : t0;
            sr2[j + 4] = ctrl ? t0 : t1;
            t0 = si2[j]; t1 = si2[j + 4];
            si2[j]     = ctrl ? t1 : t0;
            si2[j + 4] = ctrl ? t0 : t1;
        }
    }
    perm678(sr2);
    perm678(si2);
    // q=9: control = element bit, target = lane bit5
#pragma unroll
    for (int j = 0; j < 8; ++j) {
        sr2[j].y = __shfl_xor(sr2[j].y, 32);
        si2[j].y = __shfl_xor(si2[j].y, 32);
    }
}

__global__ __launch_bounds__(256) void quantum_kernel(
    const float* __restrict__ x, const float* __restrict__ in_W,
    const float* __restrict__ in_b, const float* __restrict__ gamma,
    const float* __restrict__ beta, const float* __restrict__ weights,
    const float* __restrict__ out_W, const float* __restrict__ out_b,
    float* __restrict__ out)
{
    __shared__ v2f lds_oW2[NQ * (DQ / 2)];   // out_W transposed: [q][d]
    __shared__ v4f ldsQ[QL * NQ * 3];        // per (l,q): Q0,Q1,Q2
    float* lds_f = (float*)lds_oW2;
    const int t = threadIdx.x;
    // stage out_W^T (div-free): 2 chunks of 256 d-values
#pragma unroll
    for (int rep = 0; rep < 2; ++rep) {
        const int d = t + rep * 256;
#pragma unroll
        for (int q = 0; q < NQ; ++q)
            lds_f[q * DQ + d] = out_W[d * NQ + q];
    }
    // per-(l,q) weight-only gate constants
    if (t < QL * NQ) {
        float w0 = weights[t * 2], w1 = weights[t * 2 + 1];
        float cy = __cosf(0.5f * w0), sy = __sinf(0.5f * w0);
        float cz = __cosf(0.5f * w1), sz = __sinf(0.5f * w1);
        float d = cy - sy, e = cy + sy;
        ldsQ[t * 3 + 0] = (v4f){-cz * sy,  sz * sy,  cz * cy,  sz * cy};
        ldsQ[t * 3 + 1] = (v4f){ cz * e,  -sz * e,  -cz * d,  -sz * d};
        ldsQ[t * 3 + 2] = (v4f){-sz * d,  -cz * d,   sz * e,  -cz * e};
    }
    __syncthreads();

    const int lane = t & 63;
    const int tok = blockIdx.x * 4 + (t >> 6);

    // composed CNOT lane permutation (q0..4) source lane, hoisted
    int srcl = lane;
#pragma unroll
    for (int q = 4; q >= 0; --q) {
        const int bc = 5 - q, bt = bc - 1;
        srcl ^= ((srcl >> bc) & 1) << bt;
    }

    // ---------------- stage 1: h = tanh(x @ in_W^T + in_b), then LN ----------
    const v2f* xrow2 = (const v2f*)(x + (size_t)tok * DQ);
    const v2f* inW2 = (const v2f*)in_W;
    v2f hv[NQ];
#pragma unroll
    for (int q = 0; q < NQ; ++q) hv[q] = (v2f){0.f, 0.f};
#pragma unroll
    for (int k = 0; k < 4; ++k) {
        v2f xk = xrow2[lane + 64 * k];
#pragma unroll
        for (int q = 0; q < NQ; ++q)
            hv[q] = xk * inW2[q * (DQ / 2) + lane + 64 * k] + hv[q];
    }
    float h[NQ];
#pragma unroll
    for (int q = 0; q < NQ; ++q) h[q] = hv[q].x + hv[q].y;
    reduce10(h);

    float mu = 0.f;
#pragma unroll
    for (int q = 0; q < NQ; ++q) {
        float e = __expf(2.f * (h[q] + in_b[q]));
        h[q] = (e - 1.f) * __builtin_amdgcn_rcpf(e + 1.f);
        mu += h[q];
    }
    mu *= 0.1f;
    float var = 0.f;
#pragma unroll
    for (int q = 0; q < NQ; ++q) { float d0 = h[q] - mu; var += d0 * d0; }
    var *= 0.1f;
    const float rstd = rsqrtf(var + 1e-5f);

    float cq[NQ], sq[NQ];
#pragma unroll
    for (int q = 0; q < NQ; ++q) {
        float f = (h[q] - mu) * rstd * gamma[q] + beta[q];
        float hf = 0.5f * f;
        cq[q] = __cosf(hf);
        sq[q] = __sinf(hf);
    }

    // ---------------- layer 0: product state built directly -----------------
    v2f sr2[8], si2[8];
    {
        const v4f* Q0 = &ldsQ[0];
        // lane factor from q0..q5
        v4f f0 = coef(Q0 + 0, cq[0], sq[0]);
        bool b0 = (lane & 32);
        float Lr = b0 ? f0.z : f0.x, Li = b0 ? f0.w : f0.y;
#pragma unroll
        for (int q = 1; q < 6; ++q) {
            v4f f = coef(Q0 + 3 * q, cq[q], sq[q]);
            bool b = lane & (1 << (5 - q));
            float fr = b ? f.z : f.x, fi = b ? f.w : f.y;
            float nr = Lr * fr - Li * fi, ni = Lr * fi + Li * fr;
            Lr = nr; Li = ni;
        }
        float Pr[8], Pi[8];
        {   // q6 -> j bit2
            v4f f6 = coef(Q0 + 18, cq[6], sq[6]);
            Pr[0] = Lr * f6.x - Li * f6.y; Pi[0] = Lr * f6.y + Li * f6.x;
            Pr[4] = Lr * f6.z - Li * f6.w; Pi[4] = Lr * f6.w + Li * f6.z;
        }
        {   // q7 -> j bit1
            v4f f7 = coef(Q0 + 21, cq[7], sq[7]);
#pragma unroll
            for (int jj = 0; jj < 8; jj += 4) {
                float tr1 = Pr[jj] * f7.z - Pi[jj] * f7.w;
                float ti1 = Pr[jj] * f7.w + Pi[jj] * f7.z;
                float tr0 = Pr[jj] * f7.x - Pi[jj] * f7.y;
                float ti0 = Pr[jj] * f7.y + Pi[jj] * f7.x;
                Pr[jj] = tr0; Pi[jj] = ti0; Pr[jj + 2] = tr1; Pi[jj + 2] = ti1;
            }
        }
        {   // q8 -> j bit0
            v4f f8 = coef(Q0 + 24, cq[8], sq[8]);
#pragma unroll
            for (int jj = 0; jj < 8; jj += 2) {
                float tr1 = Pr[jj] * f8.z - Pi[jj] * f8.w;
                float ti1 = Pr[jj] * f8.w + Pi[jj] * f8.z;
                float tr0 = Pr[jj] * f8.x - Pi[jj] * f8.y;
                float ti0 = Pr[jj] * f8.y + Pi[jj] * f8.x;
                Pr[jj] = tr0; Pi[jj] = ti0; Pr[jj + 1] = tr1; Pi[jj + 1] = ti1;
            }
        }
        {   // q9 -> element
            v4f f9 = coef(Q0 + 27, cq[9], sq[9]);
            v2f c9r = {f9.x, f9.z}, c9i = {f9.y, f9.w};
#pragma unroll
            for (int j = 0; j < 8; ++j) {
                sr2[j] = Pr[j] * c9r - Pi[j] * c9i;
                si2[j] = Pr[j] * c9i + Pi[j] * c9r;
            }
        }
    }
    cnot_ring(sr2, si2, lane, srcl);

    // ---------------- layers 1..3: one fused SU(2) gate per qubit ------------
#pragma unroll 1
    for (int l = 1; l < QL; ++l) {
        const v4f* Ql = &ldsQ[l * NQ * 3];
        gate_lane<32>(sr2, si2, coef(Ql + 0,  cq[0], sq[0]), lane & 32);
        gate_lane< 8>(sr2, si2, coef(Ql + 6,  cq[2], sq[2]), lane & 8);
        gate_lane<16>(sr2, si2, coef(Ql + 3,  cq[1], sq[1]), lane & 16);
        gate_lane< 2>(sr2, si2, coef(Ql + 12, cq[4], sq[4]), lane & 2);
        gate_lane< 4>(sr2, si2, coef(Ql + 9,  cq[3], sq[3]), lane & 4);
        gate_lane< 1>(sr2, si2, coef(Ql + 15, cq[5], sq[5]), lane & 1);
        gate_reg<4>(sr2, si2, coef(Ql + 18, cq[6], sq[6]));
        gate_reg<2>(sr2, si2, coef(Ql + 21, cq[7], sq[7]));
        gate_reg<1>(sr2, si2, coef(Ql + 24, cq[8], sq[8]));
        gate_elem(sr2, si2, coef(Ql + 27, cq[9], sq[9]));
        cnot_ring(sr2, si2, lane, srcl);
    }

    // ---------------- measurement -------------------------------------------
    v2f aP = {0.f, 0.f}, a6 = {0.f, 0.f}, a7 = {0.f, 0.f}, a8 = {0.f, 0.f};
#pragma unroll
    for (int j = 0; j < 8; ++j) {
        v2f p = sr2[j] * sr2[j] + si2[j] * si2[j];
        aP += p;
        if (j & 4) a6 -= p; else a6 += p;
        if (j & 2) a7 -= p; else a7 += p;
        if (j & 1) a8 -= p; else a8 += p;
    }
    const float P = aP.x + aP.y;
    float z[NQ];
#pragma unroll
    for (int q = 0; q < 6; ++q)
        z[q] = (lane & (1 << (5 - q))) ? -P : P;
    z[6] = a6.x + a6.y; z[7] = a7.x + a7.y; z[8] = a8.x + a8.y;
    z[9] = aP.x - aP.y;
    reduce10(z);

    // ---------------- epilogue: out = x + z @ out_W^T + out_b ----------------
    v2f* orow2 = (v2f*)(out + (size_t)tok * DQ);
    const v2f* ob2 = (const v2f*)out_b;
#pragma unroll
    for (int k = 0; k < 4; ++k) {
        const int d2 = lane + 64 * k;
        v2f acc = xrow2[d2] + ob2[d2];
#pragma unroll
        for (int q = 0; q < NQ; ++q)
            acc = z[q] * lds_oW2[q * (DQ / 2) + d2] + acc;
        orow2[d2] = acc;
    }
}

extern "C" void kernel_launch(void* const* d_in, const int* in_sizes, int n_in,
                              void* d_out, int out_size, void* d_ws, size_t ws_size,
                              hipStream_t stream) {
    const float* x       = (const float*)d_in[0];
    const float* in_W    = (const float*)d_in[1];
    const float* in_b    = (const float*)d_in[2];
    const float* gamma   = (const float*)d_in[3];
    const float* beta    = (const float*)d_in[4];
    const float* weights = (const float*)d_in[5];
    const float* out_W   = (const float*)d_in[6];
    const float* out_b   = (const float*)d_in[7];
    float* out = (float*)d_out;

    dim3 grid(NTOK / 4), block(256);
    hipLaunchKernelGGL(quantum_kernel, grid, block, 0, stream,
                       x, in_W, in_b, gamma, beta, weights, out_W, out_b, out);
}